// Round 18
// baseline (247.847 us; speedup 1.0000x reference)
//
#include <hip/hip_runtime.h>
#include <hip/hip_bf16.h>
#include <math.h>

#define Bb 256
#define Tt 1024
#define Ll 128

typedef short s8v  __attribute__((ext_vector_type(8)));
typedef float f32x4 __attribute__((ext_vector_type(4)));

__device__ __forceinline__ short f2bf(float x) {   // RNE f32 -> bf16 bits
    unsigned u = __float_as_uint(x);
    unsigned r = (u + 0x7FFFu + ((u >> 16) & 1u)) >> 16;
    return (short)r;
}
__device__ __forceinline__ float bf2f(unsigned short u) {
    return __uint_as_float(((unsigned)u) << 16);
}

// ---------------- fully fused CRF kernel (MFMA scan) ----------------
// R17 structure (grid 256, 4 waves, MFMA GEMV scan, bf16 p exchange, slot
// refill, 4-step recenter, LDS-only barrier) with two critical-path cuts:
//  * exp-prep moved INTO the ds_read shadow: body t computes its own
//    EXc = expf(h[t])*m[t] right after issuing the A-fragment reads (was:
//    computed in body t-1 BETWEEN write and barrier, delaying every
//    barrier by ~35cy). Slot consumed and refilled in the same body.
//  * MFMA tree depth 4 -> 2: two independent 2-chains per tile + scalar
//    add of D[0] (D rows all equal since A rows all equal p). Halves the
//    dependent-MFMA latency on the serial path.
__global__ __launch_bounds__(256)
__attribute__((amdgpu_waves_per_eu(1, 1)))
void crf_fused_kernel(
    const float* __restrict__ h, const int* __restrict__ labels,
    const float* __restrict__ mask, const float* __restrict__ trans,
    const float* __restrict__ start_trans, const float* __restrict__ end_trans,
    float* __restrict__ out)
{
    __shared__ __align__(16) unsigned short pbuf[2][Ll];  // bf16 p, 256B each
    __shared__ float mk_lds[Tt + 4];
    __shared__ float redm[4], reds[4], racc[4], rmsum[4];

    const int b = blockIdx.x;
    const int tid = threadIdx.x;
    const int wave = tid >> 6;
    const int lane = tid & 63;
    const int l15 = lane & 15;
    const int l4  = lane >> 4;
    const int w32 = wave << 5;
    const bool wr16 = (lane < 16);
    const int jT0 = w32 + l15;          // this lane's tile-0 column
    const int jT1 = w32 + 16 + l15;     // tile-1 column

    const float* hb = h + (size_t)b * Tt * Ll;
    const float* mk = mask + b * Tt;
    const int* lab = labels + b * Tt;

    // stage mask row into LDS
    ((float4*)mk_lds)[tid] = ((const float4*)mk)[tid];

    // ---- fused num partials ----
    float nacc = 0.f, nms = 0.f;
    #pragma unroll
    for (int r = 0; r < 4; ++r) {
        int t = tid + (r << 8);
        float mt = mk[t];
        nms += mt;
        if (t < Tt - 1) {
            int lt = lab[t], lt1 = lab[t + 1];
            nacc += hb[t * Ll + lt] * mt + trans[lt * Ll + lt1] * mk[t + 1];
        }
    }

    // ---- B fragments: E[k][j] bf16, 2 tiles x 4 K-chunks ----
#define MKB(c, J) ({ const float* tb = trans + (size_t)((c) * 32 + l4 * 8) * Ll + (J); \
    s8v r_; r_[0]=f2bf(__expf(tb[0]));      r_[1]=f2bf(__expf(tb[Ll]));     \
            r_[2]=f2bf(__expf(tb[2*Ll]));   r_[3]=f2bf(__expf(tb[3*Ll]));   \
            r_[4]=f2bf(__expf(tb[4*Ll]));   r_[5]=f2bf(__expf(tb[5*Ll]));   \
            r_[6]=f2bf(__expf(tb[6*Ll]));   r_[7]=f2bf(__expf(tb[7*Ll])); r_; })
    s8v B00 = MKB(0, jT0), B01 = MKB(1, jT0), B02 = MKB(2, jT0), B03 = MKB(3, jT0);
    s8v B10 = MKB(0, jT1), B11 = MKB(1, jT1), B12 = MKB(2, jT1), B13 = MKB(3, jT1);
#undef MKB

    // bootstrap t = 0: shift S0 = score_0[0] + 16 (uniform)
    float S = start_trans[0] + hb[0] + 16.0f;
    if (tid < Ll) {
        float sc0 = start_trans[tid] + hb[tid];
        pbuf[0][tid] = (unsigned short)f2bf(__expf(sc0 - S));
    }
    float pwA = __expf(start_trans[jT0] + hb[jT0] - S);
    float pwB = __expf(start_trans[jT1] + hb[jT1] - S);

    // h/mask slots (slot r holds data for time t with t&3 == r)
    float h1a = hb[1 * Ll + jT0], h1b = hb[1 * Ll + jT1], m1 = mk[1];
    float h2a = hb[2 * Ll + jT0], h2b = hb[2 * Ll + jT1], m2 = mk[2];
    float h3a = hb[3 * Ll + jT0], h3b = hb[3 * Ll + jT1], m3 = mk[3];
    float h0a = hb[4 * Ll + jT0], h0b = hb[4 * Ll + jT1], m0 = mk[4];
    __syncthreads();

    float4 MQ;
    const f32x4 Zac = {0.f, 0.f, 0.f, 0.f};

    // BODY(t): consumes slot (HRa,HRb,MR) = (h[t],m[t]), refills the SAME
    // slot with time TR = t+4 (use-before-overwrite; load consumed 4 bodies
    // later -> never waited on). EXc computed HERE, inside the ds_read
    // shadow. MFMA: two 2-chains per tile, scalar add of elem 0.
#define BODY(RBUF, UPD, HRa, HRb, MR, TR, MV, LQ) {                      \
    const unsigned short* pb_ = pbuf[RBUF];                              \
    s8v a0 = *(const s8v*)(pb_ + l4 * 8);                                \
    s8v a1 = *(const s8v*)(pb_ + 32 + l4 * 8);                           \
    s8v a2 = *(const s8v*)(pb_ + 64 + l4 * 8);                           \
    s8v a3 = *(const s8v*)(pb_ + 96 + l4 * 8);                           \
    float pz = 0.f;                                                      \
    if (UPD) pz = bf2f(pb_[0]);                                          \
    float c1a = __expf(HRa) * MR;                                        \
    float c1b = __expf(HRb) * MR;                                        \
    float OMc = 1.f - MR;                                                \
    HRa = hb[(TR) * Ll + jT0];                                           \
    HRb = hb[(TR) * Ll + jT1];                                           \
    MR = (MV);                                                           \
    if (LQ) MQ = *(const float4*)(&mk_lds[(TR) + 1]);                    \
    float c0a = pwA * OMc, c0b = pwB * OMc;                              \
    if (UPD) { float ed = __fdividef(1.12535175e-7f, pz);                \
               c1a *= ed; c1b *= ed; c0a *= ed; c0b *= ed;               \
               S += __logf(pz) + 16.0f; }                                \
    f32x4 acA0 = __builtin_amdgcn_mfma_f32_16x16x32_bf16(a0, B00, Zac, 0, 0, 0); \
    acA0 = __builtin_amdgcn_mfma_f32_16x16x32_bf16(a1, B01, acA0, 0, 0, 0);      \
    f32x4 acA1 = __builtin_amdgcn_mfma_f32_16x16x32_bf16(a2, B02, Zac, 0, 0, 0); \
    acA1 = __builtin_amdgcn_mfma_f32_16x16x32_bf16(a3, B03, acA1, 0, 0, 0);      \
    f32x4 acB0 = __builtin_amdgcn_mfma_f32_16x16x32_bf16(a0, B10, Zac, 0, 0, 0); \
    acB0 = __builtin_amdgcn_mfma_f32_16x16x32_bf16(a1, B11, acB0, 0, 0, 0);      \
    f32x4 acB1 = __builtin_amdgcn_mfma_f32_16x16x32_bf16(a2, B12, Zac, 0, 0, 0); \
    acB1 = __builtin_amdgcn_mfma_f32_16x16x32_bf16(a3, B13, acB1, 0, 0, 0);      \
    float s0 = acA0[0] + acA1[0];                                        \
    float s1 = acB0[0] + acB1[0];                                        \
    float pnA = fmaf(s0, c1a, c0a);                                      \
    float pnB = fmaf(s1, c1b, c0b);                                      \
    if (wr16) { pbuf[(RBUF) ^ 1][w32 + l15]      = (unsigned short)f2bf(pnA); \
                pbuf[(RBUF) ^ 1][w32 + 16 + l15] = (unsigned short)f2bf(pnB); } \
    pwA = pnA; pwB = pnB;                                                \
    __builtin_amdgcn_sched_barrier(0);                                   \
    asm volatile("s_waitcnt lgkmcnt(0)");                                \
    __builtin_amdgcn_s_barrier();                                        \
    __builtin_amdgcn_sched_barrier(0);                                   \
}

    // pre-loop bodies: t = 1, 2, 3
    BODY(0, 0, h1a, h1b, m1, 5, mk_lds[5], 0)
    BODY(1, 0, h2a, h2b, m2, 6, mk_lds[6], 0)
    BODY(0, 0, h3a, h3b, m3, 7, mk_lds[7], 1)

    // main loop: k = 1..254, t = 4k (recenter), 4k+1..4k+3; TR = t+4 <= 1023
    for (int k = 1; k < 255; ++k) {
        int t4 = k << 2;
        BODY(1, 1, h0a, h0b, m0, t4 + 4, MQ.x, 0)
        BODY(0, 0, h1a, h1b, m1, t4 + 5, MQ.y, 0)
        BODY(1, 0, h2a, h2b, m2, t4 + 6, MQ.z, 0)
        BODY(0, 0, h3a, h3b, m3, t4 + 7, MQ.w, 1)
    }
    // tail k = 255: t = 1020..1023 (refills dummy)
    BODY(1, 1, h0a, h0b, m0, Tt - 1, MQ.x, 0)
    BODY(0, 0, h1a, h1b, m1, Tt - 1, MQ.y, 0)
    BODY(1, 0, h2a, h2b, m2, Tt - 1, MQ.z, 0)
    BODY(0, 0, h3a, h3b, m3, Tt - 1, MQ.w, 0)
#undef BODY

    // ---- epilogue: den logsumexp + num reduce ----
    float v0 = __logf(pwA) + S + end_trans[jT0];
    float v1 = __logf(pwB) + S + end_trans[jT1];
    float mval = wr16 ? fmaxf(v0, v1) : -1e30f;
    #pragma unroll
    for (int off = 32; off; off >>= 1) {
        mval = fmaxf(mval, __shfl_xor(mval, off, 64));
        nacc += __shfl_down(nacc, off, 64);
        nms  += __shfl_down(nms,  off, 64);
    }
    if (lane == 0) { redm[wave] = mval; racc[wave] = nacc; rmsum[wave] = nms; }
    __syncthreads();
    float M = fmaxf(fmaxf(redm[0], redm[1]), fmaxf(redm[2], redm[3]));
    float e = wr16 ? (__expf(v0 - M) + __expf(v1 - M)) : 0.f;
    #pragma unroll
    for (int off = 32; off; off >>= 1) e += __shfl_xor(e, off, 64);
    if (lane == 0) reds[wave] = e;
    __syncthreads();
    if (tid == 0) {
        float den = M + __logf(reds[0] + reds[1] + reds[2] + reds[3]);
        float a  = racc[0] + racc[1] + racc[2] + racc[3];
        float mm = rmsum[0] + rmsum[1] + rmsum[2] + rmsum[3];
        int last_idx = (int)(mm + 0.5f) - 1;
        if (last_idx < 0) last_idx = 0;
        if (last_idx > Tt - 1) last_idx = Tt - 1;
        int last_lab = lab[last_idx];
        float num = a + start_trans[lab[0]];
        num += hb[(Tt - 1) * Ll + last_lab] * mk_lds[Tt - 1];
        num += end_trans[last_lab];
        out[b] = num - den;
    }
}

extern "C" void kernel_launch(void* const* d_in, const int* in_sizes, int n_in,
                              void* d_out, int out_size, void* d_ws, size_t ws_size,
                              hipStream_t stream) {
    const float* h           = (const float*)d_in[0];
    const int*   labels      = (const int*)d_in[1];
    const float* mask        = (const float*)d_in[2];
    const float* trans       = (const float*)d_in[3];
    const float* start_trans = (const float*)d_in[4];
    const float* end_trans   = (const float*)d_in[5];
    float* out = (float*)d_out;

    crf_fused_kernel<<<Bb, 256, 0, stream>>>(h, labels, mask, trans,
                                             start_trans, end_trans, out);
}